// Round 8
// baseline (226.673 us; speedup 1.0000x reference)
//
#include <hip/hip_runtime.h>
#include <hip/hip_bf16.h>

#define WINDOW 5
#define DIM 1024
#define FEAT 1024
#define SEQ 128
#define BATCH 128
#define MTOT (BATCH*SEQ)      // 16384
#define NTOT (WINDOW*FEAT)    // 5120
#define KTOT 1024

#define DCHUNK 16             // d-rows per partial-absmax block
#define BUFB 36864            // one buffer: A 16KB + B 20KB

typedef int int4v __attribute__((ext_vector_type(4)));

static __device__ __forceinline__ unsigned short f2bf(float f) {
  union { float f; unsigned int i; } c; c.f = f;
  unsigned int i = c.i;
  unsigned int lsb = (i >> 16) & 1u;
  i += 0x7fffu + lsb;            // round-to-nearest-even
  return (unsigned short)(i >> 16);
}
static __device__ __forceinline__ float bf2f(unsigned short u) {
  union { unsigned int i; float f; } c; c.i = ((unsigned int)u) << 16; return c.f;
}
static __device__ __forceinline__ signed char q8(float v, float inv) {
  float q = rintf(v * inv);
  q = fminf(fmaxf(q, -127.f), 127.f);
  return (signed char)(int)q;
}

// ---------------- x fp32 -> i8 with per-row scale ----------------
__global__ __launch_bounds__(256) void quant_x(const float* __restrict__ x,
                                               signed char* __restrict__ xq,
                                               float* __restrict__ sx) {
  int row  = blockIdx.x * 4 + (threadIdx.x >> 6);   // one wave per row
  int lane = threadIdx.x & 63;
  const float* xr = x + (size_t)row * KTOT;

  float4 v[4];
  float amax = 0.f;
  #pragma unroll
  for (int i = 0; i < 4; i++) {
    v[i] = ((const float4*)xr)[i * 64 + lane];
    amax = fmaxf(amax, fmaxf(fmaxf(fabsf(v[i].x), fabsf(v[i].y)),
                             fmaxf(fabsf(v[i].z), fabsf(v[i].w))));
  }
  #pragma unroll
  for (int m = 1; m < 64; m <<= 1)
    amax = fmaxf(amax, __shfl_xor(amax, m));

  float inv = amax > 0.f ? 127.f / amax : 0.f;
  int* xqr = (int*)(xq + (size_t)row * KTOT);
  #pragma unroll
  for (int i = 0; i < 4; i++) {
    int p = ((int)(unsigned char)q8(v[i].x, inv)) |
            ((int)(unsigned char)q8(v[i].y, inv) << 8) |
            ((int)(unsigned char)q8(v[i].z, inv) << 16) |
            ((int)q8(v[i].w, inv) << 24);
    xqr[i * 64 + lane] = p;
  }
  if (lane == 0) sx[row] = amax / 127.f;
}

// ---------------- per-(w,f) column absmax, stage 1: coalesced partials ----------------
__global__ __launch_bounds__(256) void w_colamax_part(const float* __restrict__ Ws,
                                                      float* __restrict__ part) {
  int w  = blockIdx.z;
  int dc = blockIdx.y;
  int f4 = threadIdx.x;
  const float* p = Ws + ((size_t)w * DIM + (size_t)dc * DCHUNK) * FEAT;
  float4 m = {0.f, 0.f, 0.f, 0.f};
  #pragma unroll
  for (int d = 0; d < DCHUNK; d++) {
    float4 v = ((const float4*)(p + (size_t)d * FEAT))[f4];
    m.x = fmaxf(m.x, fabsf(v.x));
    m.y = fmaxf(m.y, fabsf(v.y));
    m.z = fmaxf(m.z, fabsf(v.z));
    m.w = fmaxf(m.w, fabsf(v.w));
  }
  ((float4*)(part + ((size_t)w * (DIM / DCHUNK) + dc) * FEAT))[f4] = m;
}

// ---------------- stage 2: fold partials -> sw = amax/127 ----------------
__global__ __launch_bounds__(256) void w_colamax_reduce(const float* __restrict__ part,
                                                        float* __restrict__ sw) {
  int idx = blockIdx.x * 256 + threadIdx.x;   // w*1024 + f, 5120 total
  int w = idx >> 10, f = idx & 1023;
  const float* p = part + (size_t)w * (DIM / DCHUNK) * FEAT + f;
  float m = 0.f;
  #pragma unroll 8
  for (int c = 0; c < DIM / DCHUNK; c++)
    m = fmaxf(m, p[(size_t)c * FEAT]);
  sw[idx] = m / 127.f;
}

// ---------------- Ws[w][d][f] fp32 -> WqT[w][f][d] i8 ----------------
__global__ __launch_bounds__(256) void transq_ws(const float* __restrict__ Ws,
                                                 const float* __restrict__ sw,
                                                 signed char* __restrict__ wq) {
  __shared__ float tile[32][33];
  int w  = blockIdx.z;
  int f0 = blockIdx.x * 32, d0 = blockIdx.y * 32;
  int tx = threadIdx.x, ty = threadIdx.y;       // (32,8)
  const float* src = Ws + ((size_t)w * DIM + d0) * FEAT + f0;
  #pragma unroll
  for (int i = 0; i < 4; i++)
    tile[ty + 8*i][tx] = src[(size_t)(ty + 8*i) * FEAT + tx];
  __syncthreads();
  signed char* dst = wq + ((size_t)w * FEAT + f0) * DIM + d0;
  #pragma unroll
  for (int i = 0; i < 4; i++) {
    int f = f0 + ty + 8*i;
    float swv = sw[(w << 10) + f];
    float inv = swv > 0.f ? 1.0f / swv : 0.f;
    dst[(size_t)(ty + 8*i) * DIM + tx] = q8(tile[tx][ty + 8*i], inv);
  }
}

// ---------------- fused GEMM(i8) + dequant + max-plus scan + tanh ----------------
// 256 thr (4 waves, 2M x 2N), tile = 128 l (one batch) x 160 c (5w x 32f), BK=128.
// 2-deep software pipeline: 2 x 36KB LDS buffers, counted s_waitcnt vmcnt(9) + raw
// s_barrier (never drain to 0 mid-loop). Per wave per tile: exactly 4 A-segs +
// 5 B-segs = 9 global_load_lds (equal shares -> uniform vmcnt works). All LDS
// offsets / waits are literals (kt unrolled x2); 6 hoisted global ptrs +=256/iter.
// Proj tile (40KB bf16, swizzled) overlays the buffers after the K-loop.
__global__ __launch_bounds__(256, 2) void fused_gemm_scan(
    const signed char* __restrict__ xq,   // [MTOT][1024] i8
    const signed char* __restrict__ wq,   // [W*FEAT][1024] i8 (K-contiguous)
    const float* __restrict__ sx,         // [MTOT]
    const float* __restrict__ swp,        // [W*FEAT]
    const float* __restrict__ bias,       // [FEAT]
    float* __restrict__ out)              // [BATCH][FEAT]
{
  __shared__ __align__(16) char smem[2 * BUFB];   // 72 KB

  const int tid  = threadIdx.x;
  const int wid  = tid >> 6;
  const int lane = tid & 63;

  // XCD-chunked swizzle (4096 % 8 == 0 -> bijective); work = b*32 + fslice
  int bid = blockIdx.x;
  int wg  = ((bid & 7) << 9) + (bid >> 3);
  const int b  = wg >> 5;
  const int f0 = (wg & 31) << 5;

  const int wm = wid >> 1, wn = wid & 1;     // wave tile: 64 M x 80 N
  const int rowin = lane >> 3;               // row within 8-row/1KB segment
  const int swb16 = ((lane & 7) ^ rowin) << 4;  // pre-swizzled byte slot in 128B row

  // hoisted global source pointers (advance +256 per unrolled-x2 iteration)
  const char* pA = (const char*)xq + ((size_t)b * SEQ + wid * 32 + rowin) * KTOT + swb16;
  const char* pB0, *pB1, *pB2, *pB3, *pB4;
  {
    int r0 = wid * 40 + rowin;
    #define BPTR(c_) ((const char*)wq + \
        (size_t)((((r0 + 8*(c_)) >> 5) << 10) + f0 + ((r0 + 8*(c_)) & 31)) * KTOT + swb16)
    pB0 = BPTR(0); pB1 = BPTR(1); pB2 = BPTR(2); pB3 = BPTR(3); pB4 = BPTR(4);
    #undef BPTR
  }
  const int dstA = wid * 4096;           // + bufoff + c*1024
  const int dstB = 16384 + wid * 5120;   // + bufoff + c*1024

  #define AS1 __attribute__((address_space(1)))
  #define AS3 __attribute__((address_space(3)))
  #define STAGE(koff_, bufoff_) do {                                               \
    __builtin_amdgcn_global_load_lds((const AS1 void*)(pA + (koff_)),              \
        (AS3 void*)(smem + (bufoff_) + dstA),        16, 0, 0);                    \
    __builtin_amdgcn_global_load_lds((const AS1 void*)(pA + 8192 + (koff_)),       \
        (AS3 void*)(smem + (bufoff_) + dstA + 1024), 16, 0, 0);                    \
    __builtin_amdgcn_global_load_lds((const AS1 void*)(pA + 16384 + (koff_)),      \
        (AS3 void*)(smem + (bufoff_) + dstA + 2048), 16, 0, 0);                    \
    __builtin_amdgcn_global_load_lds((const AS1 void*)(pA + 24576 + (koff_)),      \
        (AS3 void*)(smem + (bufoff_) + dstA + 3072), 16, 0, 0);                    \
    __builtin_amdgcn_global_load_lds((const AS1 void*)(pB0 + (koff_)),             \
        (AS3 void*)(smem + (bufoff_) + dstB),        16, 0, 0);                    \
    __builtin_amdgcn_global_load_lds((const AS1 void*)(pB1 + (koff_)),             \
        (AS3 void*)(smem + (bufoff_) + dstB + 1024), 16, 0, 0);                    \
    __builtin_amdgcn_global_load_lds((const AS1 void*)(pB2 + (koff_)),             \
        (AS3 void*)(smem + (bufoff_) + dstB + 2048), 16, 0, 0);                    \
    __builtin_amdgcn_global_load_lds((const AS1 void*)(pB3 + (koff_)),             \
        (AS3 void*)(smem + (bufoff_) + dstB + 3072), 16, 0, 0);                    \
    __builtin_amdgcn_global_load_lds((const AS1 void*)(pB4 + (koff_)),             \
        (AS3 void*)(smem + (bufoff_) + dstB + 4096), 16, 0, 0);                    \
  } while (0)

  // ds_read bases (per-thread, swizzled); immediates carry bufoff + frag offsets
  const int r7   = (lane & 15) & 7;
  const int sx0o = (((lane >> 4) + 0) ^ r7) << 4;
  const int sx1o = (((lane >> 4) + 4) ^ r7) << 4;
  const int rA128 = (wm * 64 + (lane & 15)) * 128;
  const int rB128 = (wn * 80 + (lane & 15)) * 128;

  int4v acc[4][5];
  #pragma unroll
  for (int i = 0; i < 4; i++)
    #pragma unroll
    for (int j = 0; j < 5; j++)
      acc[i][j] = (int4v){0, 0, 0, 0};

  #define COMPUTE(bufoff_) do {                                                    \
    int4v a_[4], b_[5];                                                            \
    _Pragma("unroll")                                                              \
    for (int i = 0; i < 4; i++)                                                    \
      a_[i] = *(const int4v*)(smem + (bufoff_) + rA128 + sx0o + i * 2048);         \
    _Pragma("unroll")                                                              \
    for (int j = 0; j < 5; j++)                                                    \
      b_[j] = *(const int4v*)(smem + (bufoff_) + 16384 + rB128 + sx0o + j * 2048); \
    _Pragma("unroll")                                                              \
    for (int i = 0; i < 4; i++)                                                    \
      _Pragma("unroll")                                                            \
      for (int j = 0; j < 5; j++)                                                  \
        acc[i][j] = __builtin_amdgcn_mfma_i32_16x16x64_i8(a_[i], b_[j], acc[i][j], 0, 0, 0); \
    _Pragma("unroll")                                                              \
    for (int i = 0; i < 4; i++)                                                    \
      a_[i] = *(const int4v*)(smem + (bufoff_) + rA128 + sx1o + i * 2048);         \
    _Pragma("unroll")                                                              \
    for (int j = 0; j < 5; j++)                                                    \
      b_[j] = *(const int4v*)(smem + (bufoff_) + 16384 + rB128 + sx1o + j * 2048); \
    _Pragma("unroll")                                                              \
    for (int i = 0; i < 4; i++)                                                    \
      _Pragma("unroll")                                                            \
      for (int j = 0; j < 5; j++)                                                  \
        acc[i][j] = __builtin_amdgcn_mfma_i32_16x16x64_i8(a_[i], b_[j], acc[i][j], 0, 0, 0); \
  } while (0)

  #define SB __builtin_amdgcn_sched_barrier(0)

  // prologue: tiles 0,1 in flight (18 loads/wave)
  STAGE(0, 0);
  STAGE(128, BUFB);
  pA += 256; pB0 += 256; pB1 += 256; pB2 += 256; pB3 += 256; pB4 += 256;

  for (int kt2 = 0; kt2 < 3; kt2++) {
    asm volatile("s_waitcnt vmcnt(9)" ::: "memory");   // tile 2kt2 certified
    __builtin_amdgcn_s_barrier();
    SB;
    COMPUTE(0);
    SB;
    __builtin_amdgcn_s_barrier();                      // buf0 free
    SB;
    STAGE(0, 0);                                       // tile 2kt2+2 -> buf0
    asm volatile("s_waitcnt vmcnt(9)" ::: "memory");   // tile 2kt2+1 certified
    __builtin_amdgcn_s_barrier();
    SB;
    COMPUTE(BUFB);
    SB;
    __builtin_amdgcn_s_barrier();                      // buf1 free
    SB;
    STAGE(128, BUFB);                                  // tile 2kt2+3 -> buf1
    pA += 256; pB0 += 256; pB1 += 256; pB2 += 256; pB3 += 256; pB4 += 256;
  }
  // tiles 6 (buf0), 7 (buf1) in flight
  asm volatile("s_waitcnt vmcnt(9)" ::: "memory");
  __builtin_amdgcn_s_barrier();
  SB;
  COMPUTE(0);
  SB;
  __builtin_amdgcn_s_barrier();
  asm volatile("s_waitcnt vmcnt(0)" ::: "memory");
  __builtin_amdgcn_s_barrier();
  SB;
  COMPUTE(BUFB);

  __syncthreads();   // full drain before proj overlays the buffers

  // ---- dequant -> bf16 proj tile in LDS [128][160], byte addr ^ ((l>>2)&3)<<5 ----
  float sxv[16];
  #pragma unroll
  for (int i = 0; i < 4; i++)
    #pragma unroll
    for (int r = 0; r < 4; r++)
      sxv[i * 4 + r] = sx[b * SEQ + wm * 64 + i * 16 + ((lane >> 4) << 2) + r];
  float swv[5];
  #pragma unroll
  for (int j = 0; j < 5; j++) {
    int c = wn * 80 + j * 16 + (lane & 15);
    swv[j] = swp[((c >> 5) << 10) + f0 + (c & 31)];
  }

  #pragma unroll
  for (int i = 0; i < 4; i++) {
    #pragma unroll
    for (int j = 0; j < 5; j++) {
      #pragma unroll
      for (int r = 0; r < 4; r++) {
        int l = wm * 64 + i * 16 + ((lane >> 4) << 2) + r;
        int c = wn * 80 + j * 16 + (lane & 15);
        float v = (float)acc[i][j][r] * sxv[i * 4 + r] * swv[j];
        int byte = ((l * 160 + c) << 1) ^ (((l >> 2) & 3) << 5);
        *(unsigned short*)(smem + byte) = f2bf(v);
      }
    }
  }
  __syncthreads();

  // ---- max-plus scan over l, one thread per f-column (conflict-free reads) ----
  if (tid < 32) {
    const int f = tid;
    float h0 = 0.f, h1 = 0.f, h2 = 0.f, h3 = 0.f, h4 = 0.f;
    for (int l = 0; l < SEQ; l++) {
      const int swz  = ((l >> 2) & 3) << 5;
      const int base = l * 320;
      float p[5];
      #pragma unroll
      for (int w = 0; w < 5; w++) {
        int byte = (base + (((w << 5) + f) << 1)) ^ swz;
        p[w] = bf2f(*(const unsigned short*)(smem + byte));
      }
      h4 = fmaxf(h3 + p[4], h4);
      h3 = fmaxf(h2 + p[3], h3);
      h2 = fmaxf(h1 + p[2], h2);
      h1 = fmaxf(h0 + p[1], h1);
      h0 = fmaxf(p[0], h0);
    }
    out[b * FEAT + f0 + f] = tanhf(h4 + bias[f0 + f]);
  }
  #undef STAGE
  #undef COMPUTE
  #undef SB
  #undef AS1
  #undef AS3
}

extern "C" void kernel_launch(void* const* d_in, const int* in_sizes, int n_in,
                              void* d_out, int out_size, void* d_ws, size_t ws_size,
                              hipStream_t stream) {
  const float* x  = (const float*)d_in[0];
  const float* Ws = (const float*)d_in[1];
  const float* b  = (const float*)d_in[2];
  float* out = (float*)d_out;

  char* ws = (char*)d_ws;
  const size_t XQ_BYTES = (size_t)MTOT * KTOT;                  // 16,777,216
  const size_t WQ_BYTES = (size_t)WINDOW * FEAT * DIM;          //  5,242,880
  const size_t SX_BYTES = (size_t)MTOT * 4;                     //     65,536
  const size_t SW_BYTES = (size_t)WINDOW * FEAT * 4;            //     20,480
  signed char* xq = (signed char*)ws;
  signed char* wq = (signed char*)(ws + XQ_BYTES);
  float* sx   = (float*)(ws + XQ_BYTES + WQ_BYTES);
  float* sw   = (float*)(ws + XQ_BYTES + WQ_BYTES + SX_BYTES);
  float* part = (float*)(ws + XQ_BYTES + WQ_BYTES + SX_BYTES + SW_BYTES);

  hipLaunchKernelGGL(quant_x, dim3(MTOT / 4), dim3(256), 0, stream, x, xq, sx);
  hipLaunchKernelGGL(w_colamax_part, dim3(1, DIM / DCHUNK, WINDOW), dim3(256), 0, stream,
                     Ws, part);
  hipLaunchKernelGGL(w_colamax_reduce, dim3(NTOT / 256), dim3(256), 0, stream, part, sw);
  hipLaunchKernelGGL(transq_ws, dim3(FEAT / 32, DIM / 32, WINDOW), dim3(32, 8), 0, stream,
                     Ws, sw, wq);
  hipLaunchKernelGGL(fused_gemm_scan, dim3(BATCH * 32), dim3(256), 0, stream,
                     xq, wq, sx, sw, b, out);
}